// Round 5
// baseline (14209.424 us; speedup 1.0000x reference)
//
#include <hip/hip_runtime.h>

#define R 116
#define BATCH 1024
#define NL 4
#define RR2 13456          // R*R
#define EPSF 1e-5f
#define NZ_ELEM (BATCH * RR2)     // 13,778,944
#define NX_ELEM (BATCH * R * 3)   //    356,352

typedef unsigned short ushort_t;

__device__ __forceinline__ float bf2f(unsigned short u){
  union { unsigned int i; float f; } v; v.i = ((unsigned int)u) << 16; return v.f;
}
__device__ __forceinline__ unsigned short f2bf(float f){
  union { float ff; unsigned int i; } v; v.ff = f;
  return (unsigned short)((v.i + 0x7fffu + ((v.i >> 16) & 1u)) >> 16);
}
__device__ __forceinline__ float wsum(float v){
  #pragma unroll
  for (int o = 32; o > 0; o >>= 1) v += __shfl_xor(v, o, 64);
  return v;
}
__device__ __forceinline__ float wmaxr(float v){
  #pragma unroll
  for (int o = 32; o > 0; o >>= 1) v = fmaxf(v, __shfl_xor(v, o, 64));
  return v;
}

// ---------------- init: Z fp32 -> bf16 (8 elems/thread) ----------------
__global__ void k_initZ(const float4* __restrict__ src, uint4* __restrict__ dst, int n8){
  int idx = blockIdx.x * blockDim.x + threadIdx.x;
  int stride = gridDim.x * blockDim.x;
  for (int i = idx; i < n8; i += stride){
    float4 a = src[2*i], b = src[2*i+1];
    uint4 w;
    w.x = (unsigned)f2bf(a.x) | ((unsigned)f2bf(a.y) << 16);
    w.y = (unsigned)f2bf(a.z) | ((unsigned)f2bf(a.w) << 16);
    w.z = (unsigned)f2bf(b.x) | ((unsigned)f2bf(b.y) << 16);
    w.w = (unsigned)f2bf(b.z) | ((unsigned)f2bf(b.w) << 16);
    dst[i] = w;
  }
}

// ---------------- init: copy X fp32, zero stats ----------------
__global__ void k_initX(const float* __restrict__ src, float* __restrict__ dst, int n,
                        float* __restrict__ stats, int nstats){
  int idx = blockIdx.x * blockDim.x + threadIdx.x;
  int stride = gridDim.x * blockDim.x;
  for (int i = idx; i < n; i += stride) dst[i] = src[i];
  for (int i = idx; i < nstats; i += stride) stats[i] = 0.f;
}

// ---------------- heavy per-graph attention + edge/node update pre-BN ----------------
// Algebra: P = softmax(K^T K) row-wise; W = P @ aw2 ; s[j] = P[j,:].ab2
//          M[i,j] = dot(Z[i,:], W[j,:]) + s[j]   (== A[b, pos1=i, pos2=j])
//          T1 = M @ Z ; Z1 = T1 @ ew^T + eb
//          T1x = M @ X ; X1 = T1x @ nw^T + nb
__launch_bounds__(1024)
__global__ void k_attn(const float* __restrict__ Xc, const ushort_t* __restrict__ Zc,
                       ushort_t* __restrict__ Z1, float* __restrict__ X1,
                       const float* __restrict__ aw1, const float* __restrict__ ab1,
                       const float* __restrict__ aw2, const float* __restrict__ ab2,
                       const float* __restrict__ nw,  const float* __restrict__ nb,
                       const float* __restrict__ ew,  const float* __restrict__ eb,
                       int layer)
{
  __shared__ float bufA[RR2];   // P, then M
  __shared__ float bufB[RR2];   // W, then T1
  __shared__ float Ksm[3 * R];
  __shared__ float ssm[R];

  const int b    = blockIdx.x;
  const int tid  = threadIdx.x;
  const int lane = tid & 63;
  const int wave = tid >> 6;
  const int nwv  = blockDim.x >> 6;     // 16 waves

  const float*    Xb = Xc + (size_t)b * R * 3;
  const ushort_t* Zb = Zc + (size_t)b * RR2;
  const float* aw1l = aw1 + layer * 9;
  const float* ab1l = ab1 + layer * 3;
  const float* aw2l = aw2 + layer * RR2;
  const float* ab2l = ab2 + layer * R;
  const float* ewl  = ew  + layer * RR2;
  const float* ebl  = eb  + layer * R;
  const float* nwl  = nw  + layer * 9;
  const float* nbl  = nb  + layer * 3;

  // 1. K[o,n] = sum_c aw1[o,c] X[n,c] + ab1[o]
  if (tid < R){
    float x0 = Xb[tid*3+0], x1 = Xb[tid*3+1], x2 = Xb[tid*3+2];
    #pragma unroll
    for (int o = 0; o < 3; o++){
      Ksm[o*R + tid] = ab1l[o] + aw1l[o*3+0]*x0 + aw1l[o*3+1]*x1 + aw1l[o*3+2]*x2;
    }
  }
  __syncthreads();

  // 2. P rows (softmax) -> bufA ; ssm[n] = P[n,:].ab2
  for (int n = wave; n < R; n += nwv){
    float k0 = Ksm[n], k1 = Ksm[R+n], k2 = Ksm[2*R+n];
    int m0 = lane, m1 = lane + 64;
    float a0 = k0*Ksm[m0] + k1*Ksm[R+m0] + k2*Ksm[2*R+m0];
    float a1 = (m1 < R) ? (k0*Ksm[m1] + k1*Ksm[R+m1] + k2*Ksm[2*R+m1]) : -1e30f;
    float mx = wmaxr(fmaxf(a0, a1));
    float e0 = __expf(a0 - mx);
    float e1 = (m1 < R) ? __expf(a1 - mx) : 0.f;
    float sm = wsum(e0 + e1);
    float sab = wsum(e0 * ab2l[m0] + ((m1 < R) ? e1 * ab2l[m1] : 0.f));
    float inv = 1.f / sm;
    bufA[n*R + m0] = e0 * inv;
    if (m1 < R) bufA[n*R + m1] = e1 * inv;
    if (lane == 0) ssm[n] = sab * inv;
  }
  __syncthreads();

  // 3. W = P @ aw2 -> bufB
  for (int j = wave; j < R; j += nwv){
    const float* Prow = bufA + j * R;
    float acc0 = 0.f, acc1 = 0.f;
    for (int k = 0; k < R; k++){
      float p = Prow[k];                         // LDS broadcast
      const float* arow = aw2l + k * R;          // coalesced fp32 (L1/L2)
      acc0 += p * arow[lane];
      if (lane + 64 < R) acc1 += p * arow[lane + 64];
    }
    bufB[j*R + lane] = acc0;
    if (lane + 64 < R) bufB[j*R + lane + 64] = acc1;
  }
  __syncthreads();

  // 4. M = Z @ W^T + s -> bufA (overwrite P). Lane-rotated c vs LDS bank conflicts.
  for (int i = wave; i < R; i += nwv){
    int j0 = lane, j1 = lane + 64;
    int rot = lane & 31;
    float acc0 = 0.f, acc1 = 0.f;
    for (int cc = 0; cc < R; cc++){
      int c = cc + rot; if (c >= R) c -= R;
      float z = bf2f(Zb[i*R + c]);               // L1-resident row (bf16)
      acc0 += z * bufB[j0*R + c];
      if (j1 < R) acc1 += z * bufB[j1*R + c];
    }
    bufA[i*R + j0] = acc0 + ssm[j0];
    if (j1 < R) bufA[i*R + j1] = acc1 + ssm[j1];
  }
  __syncthreads();

  // 5. T1 = M @ Z -> bufB (overwrite W)
  for (int n = wave; n < R; n += nwv){
    const float* Mrow = bufA + n * R;
    int c0 = lane, c1 = lane + 64;
    float acc0 = 0.f, acc1 = 0.f;
    for (int m = 0; m < R; m++){
      float p = Mrow[m];                         // LDS broadcast
      acc0 += p * bf2f(Zb[m*R + c0]);            // coalesced (bf16, L1)
      if (c1 < R) acc1 += p * bf2f(Zb[m*R + c1]);
    }
    bufB[n*R + c0] = acc0;
    if (c1 < R) bufB[n*R + c1] = acc1;
  }
  __syncthreads();

  // 6. Z1 = T1 @ ew^T + eb -> global (bf16)
  for (int n = wave; n < R; n += nwv){
    const float* Trow = bufB + n * R;
    int e0 = lane, e1 = lane + 64;
    float acc0 = ebl[e0];
    float acc1 = (e1 < R) ? ebl[e1] : 0.f;
    for (int c = 0; c < R; c++){
      float t = Trow[c];                         // LDS broadcast
      acc0 += t * ewl[e0*R + c];
      if (e1 < R) acc1 += t * ewl[e1*R + c];
    }
    Z1[(size_t)b*RR2 + n*R + e0] = f2bf(acc0);
    if (e1 < R) Z1[(size_t)b*RR2 + n*R + e1] = f2bf(acc1);
  }

  // 7. X path: T1x = M @ X ; X1 = T1x @ nw^T + nb (M in bufA untouched)
  for (int n = wave; n < R; n += nwv){
    const float* Mrow = bufA + n * R;
    float t0 = 0.f, t1 = 0.f, t2 = 0.f;
    for (int m = lane; m < R; m += 64){
      float p = Mrow[m];
      const float* xr = Xb + m * 3;
      t0 += p * xr[0]; t1 += p * xr[1]; t2 += p * xr[2];
    }
    t0 = wsum(t0); t1 = wsum(t1); t2 = wsum(t2);
    if (lane < 3){
      int e = lane;
      float v = nbl[e] + t0*nwl[e*3+0] + t1*nwl[e*3+1] + t2*nwl[e*3+2];
      X1[((size_t)b*R + n)*3 + e] = v;
    }
  }
}

// ---------------- BN stats for Z1: per-channel n, over (b, c) ----------------
__global__ void k_zstats(const ushort_t* __restrict__ Z1, float* __restrict__ zsum,
                         float* __restrict__ zsq, int layer){
  int n = blockIdx.x;           // 0..115
  int s = blockIdx.y;           // 0..15 batch slice of 64
  int tid = threadIdx.x;
  float sum = 0.f, sq = 0.f;
  for (int idx = tid; idx < 64 * R; idx += 256){
    int bl = idx / R;
    int c  = idx - bl * R;
    float v = bf2f(Z1[((size_t)(s*64 + bl) * R + n) * R + c]);
    sum += v; sq += v * v;
  }
  sum = wsum(sum); sq = wsum(sq);
  __shared__ float s1[4], s2[4];
  int lane = tid & 63, wave = tid >> 6;
  if (lane == 0){ s1[wave] = sum; s2[wave] = sq; }
  __syncthreads();
  if (tid == 0){
    atomicAdd(&zsum[layer*R + n], s1[0]+s1[1]+s1[2]+s1[3]);
    atomicAdd(&zsq [layer*R + n], s2[0]+s2[1]+s2[2]+s2[3]);
  }
}

// ---------------- BN stats for X1 ----------------
__global__ void k_xstats(const float* __restrict__ X1, float* __restrict__ xsum,
                         float* __restrict__ xsq, int layer){
  int n = blockIdx.x;
  int tid = threadIdx.x;
  float sum = 0.f, sq = 0.f;
  for (int idx = tid; idx < BATCH * 3; idx += 256){
    int bl = idx / 3, c = idx - bl * 3;
    float v = X1[((size_t)bl * R + n) * 3 + c];
    sum += v; sq += v * v;
  }
  sum = wsum(sum); sq = wsum(sq);
  __shared__ float s1[4], s2[4];
  int lane = tid & 63, wave = tid >> 6;
  if (lane == 0){ s1[wave] = sum; s2[wave] = sq; }
  __syncthreads();
  if (tid == 0){
    xsum[layer*R + n] = s1[0]+s1[1]+s1[2]+s1[3];
    xsq [layer*R + n] = s2[0]+s2[1]+s2[2]+s2[3];
  }
}

// ---------------- apply BN+relu+residual to Z (bf16 in/out) ----------------
__global__ void k_bnz(const ushort_t* __restrict__ Z1, ushort_t* __restrict__ Zc,
                      const float* __restrict__ zsum, const float* __restrict__ zsq,
                      const float* __restrict__ geg, const float* __restrict__ geb,
                      int layer){
  const float cnt = (float)(BATCH * R);
  int i = blockIdx.x * blockDim.x + threadIdx.x;
  int stride = gridDim.x * blockDim.x;
  for (int idx = i; idx < BATCH * RR2; idx += stride){
    int n = (idx / R) % R;
    float m = zsum[layer*R + n] / cnt;
    float v = fmaxf(zsq[layer*R + n] / cnt - m * m, 0.f);
    float rs = rsqrtf(v + EPSF);
    float val = (bf2f(Z1[idx]) - m) * rs * geg[layer*R + n] + geb[layer*R + n];
    Zc[idx] = f2bf(fmaxf(val, 0.f) + bf2f(Zc[idx]));
  }
}

__global__ void k_bnx(const float* __restrict__ X1, float* __restrict__ Xc,
                      const float* __restrict__ xsum, const float* __restrict__ xsq,
                      const float* __restrict__ gng, const float* __restrict__ gnb,
                      int layer){
  const float cnt = (float)(BATCH * 3);
  int idx = blockIdx.x * blockDim.x + threadIdx.x;   // exactly BATCH*R*3 threads
  if (idx >= BATCH * R * 3) return;
  int n = (idx / 3) % R;
  float m = xsum[layer*R + n] / cnt;
  float v = fmaxf(xsq[layer*R + n] / cnt - m * m, 0.f);
  float rs = rsqrtf(v + EPSF);
  float val = (X1[idx] - m) * rs * gng[layer*R + n] + gnb[layer*R + n];
  Xc[idx] = fmaxf(val, 0.f) + Xc[idx];
}

// ---------------- down-sample node ----------------
__global__ void k_dnode(const float* __restrict__ Xc, const float* __restrict__ dnw,
                        const float* __restrict__ dnb, float* __restrict__ fn,
                        float* __restrict__ dnS, int t){
  int idx = blockIdx.x * 256 + threadIdx.x;    // exactly BATCH*R
  float w0 = dnw[t*3+0], w1 = dnw[t*3+1], w2 = dnw[t*3+2];
  float bb = dnb[t];
  const float* x = Xc + (size_t)idx * 3;
  float f = fmaxf(w0*x[0] + w1*x[1] + w2*x[2] + bb, 0.f);
  fn[idx] = f;
  float s = wsum(f), q = wsum(f * f);
  __shared__ float s1[4], s2[4];
  int lane = threadIdx.x & 63, wave = threadIdx.x >> 6;
  if (lane == 0){ s1[wave] = s; s2[wave] = q; }
  __syncthreads();
  if (threadIdx.x == 0){
    atomicAdd(&dnS[t*2+0], s1[0]+s1[1]+s1[2]+s1[3]);
    atomicAdd(&dnS[t*2+1], s2[0]+s2[1]+s2[2]+s2[3]);
  }
}

__global__ void k_dnode_apply(const float* __restrict__ fn, const float* __restrict__ dnS,
                              const float* __restrict__ dng, const float* __restrict__ dnbe,
                              ushort_t* __restrict__ XZ, int t){
  int idx = blockIdx.x * 256 + threadIdx.x;    // BATCH*R
  const float cnt = (float)(BATCH * R);
  float m = dnS[t*2+0] / cnt;
  float v = fmaxf(dnS[t*2+1] / cnt - m * m, 0.f);
  float h = (fn[idx] - m) * rsqrtf(v + EPSF) * dng[t] + dnbe[t];
  int bi = idx / R, r = idx - bi * R;
  XZ[(size_t)bi * 2320 + t*R + r] = f2bf(h);
}

// ---------------- down-sample edge ----------------
__global__ void k_dedge(const ushort_t* __restrict__ Zc, const float* __restrict__ dew,
                        const float* __restrict__ deb, float* __restrict__ fe,
                        float* __restrict__ deS, int t){
  __shared__ float wsm[78];
  if (threadIdx.x < 78) wsm[threadIdx.x] = dew[t*78 + threadIdx.x];
  __syncthreads();
  int idx = blockIdx.x * 256 + threadIdx.x;    // BATCH*R rows
  const ushort_t* x = Zc + (size_t)idx * R;
  float bb = deb[t];
  float f0 = 0.f, f1 = 0.f, f2 = 0.f;
  for (int j = 0; j < 78; j++){
    float w = wsm[j];
    if (j >= 39) f0 += w * bf2f(x[j - 39]);
    f1 += w * bf2f(x[j]);
    if (j < 77)  f2 += w * bf2f(x[j + 39]);
  }
  f0 = fmaxf(f0 + bb, 0.f); f1 = fmaxf(f1 + bb, 0.f); f2 = fmaxf(f2 + bb, 0.f);
  fe[(size_t)idx*3 + 0] = f0; fe[(size_t)idx*3 + 1] = f1; fe[(size_t)idx*3 + 2] = f2;
  float s = wsum(f0 + f1 + f2), q = wsum(f0*f0 + f1*f1 + f2*f2);
  __shared__ float s1[4], s2[4];
  int lane = threadIdx.x & 63, wave = threadIdx.x >> 6;
  if (lane == 0){ s1[wave] = s; s2[wave] = q; }
  __syncthreads();
  if (threadIdx.x == 0){
    atomicAdd(&deS[t*2+0], s1[0]+s1[1]+s1[2]+s1[3]);
    atomicAdd(&deS[t*2+1], s2[0]+s2[1]+s2[2]+s2[3]);
  }
}

__global__ void k_dedge_apply(const float* __restrict__ fe, const float* __restrict__ deS,
                              const float* __restrict__ deg, const float* __restrict__ debe,
                              ushort_t* __restrict__ XZ, int t){
  int idx = blockIdx.x * 256 + threadIdx.x;    // BATCH*R*3
  const float cnt = (float)(BATCH * R * 3);
  float m = deS[t*2+0] / cnt;
  float v = fmaxf(deS[t*2+1] / cnt - m * m, 0.f);
  float h = (fe[idx] - m) * rsqrtf(v + EPSF) * deg[t] + debe[t];
  int bi = idx / (R * 3), rem = idx - bi * (R * 3);
  XZ[(size_t)bi * 2320 + 5*R + t*3*R + rem] = f2bf(h);
}

// ---------------- classifier ----------------
__launch_bounds__(256)
__global__ void k_fc1(const ushort_t* __restrict__ XZ, const float* __restrict__ cw1,
                      const float* __restrict__ cb1, float* __restrict__ H){
  __shared__ __align__(16) float xz[2320];
  int b = blockIdx.x, tid = threadIdx.x;
  for (int k = tid; k < 2320; k += 256) xz[k] = bf2f(XZ[(size_t)b * 2320 + k]);
  __syncthreads();
  const float4* xzv = (const float4*)xz;   // 580 vec4
  #pragma unroll
  for (int q = 0; q < 4; q++){
    int j = tid + 256 * q;
    const float4* wr = (const float4*)(cw1 + (size_t)j * 2320);
    float acc = cb1[j];
    #pragma unroll 4
    for (int kk = 0; kk < 580; kk++){
      float4 w4 = wr[kk];
      float4 x4 = xzv[kk];
      acc += w4.x*x4.x + w4.y*x4.y + w4.z*x4.z + w4.w*x4.w;
    }
    H[(size_t)b * 1024 + j] = fmaxf(acc, 0.f);
  }
}

__global__ void k_fc2(const float* __restrict__ H, const float* __restrict__ cw2,
                      const float* __restrict__ cb2, float* __restrict__ out){
  int b = blockIdx.x, tid = threadIdx.x;
  float a0 = 0.f, a1 = 0.f;
  for (int j = tid; j < 1024; j += 256){
    float h = H[(size_t)b * 1024 + j];
    a0 += h * cw2[j];
    a1 += h * cw2[1024 + j];
  }
  a0 = wsum(a0); a1 = wsum(a1);
  __shared__ float s0[4], s1[4];
  int lane = tid & 63, wave = tid >> 6;
  if (lane == 0){ s0[wave] = a0; s1[wave] = a1; }
  __syncthreads();
  if (tid == 0){
    out[b*2 + 0] = s0[0]+s0[1]+s0[2]+s0[3] + cb2[0];   // fp32 output (reference dtype)
    out[b*2 + 1] = s1[0]+s1[1]+s1[2]+s1[3] + cb2[1];
  }
}

extern "C" void kernel_launch(void* const* d_in, const int* in_sizes, int n_in,
                              void* d_out, int out_size, void* d_ws, size_t ws_size,
                              hipStream_t stream)
{
  // Established: inputs fp32 (bf16 reads NaN-flooded in R1/R2; R3's detector took
  // the fp32 path — its error coincided with R4's hardcoded-fp32). Output fp32
  // per the reference's jnp.float32 return (R3/R4's absmax 2.23 > zero-output
  // error 1.68 matches the bf16-written/fp32-read interleave artifact).
  const float* Xin  = (const float*)d_in[0];
  const float* Zin  = (const float*)d_in[1];
  const float* aw1  = (const float*)d_in[2];
  const float* ab1  = (const float*)d_in[3];
  const float* aw2  = (const float*)d_in[4];
  const float* ab2  = (const float*)d_in[5];
  const float* nw   = (const float*)d_in[6];
  const float* nb   = (const float*)d_in[7];
  const float* ew   = (const float*)d_in[8];
  const float* eb   = (const float*)d_in[9];
  const float* gng  = (const float*)d_in[10];
  const float* gnb  = (const float*)d_in[11];
  const float* geg  = (const float*)d_in[12];
  const float* geb  = (const float*)d_in[13];
  const float* dnw  = (const float*)d_in[14];
  const float* dnb  = (const float*)d_in[15];
  const float* dng  = (const float*)d_in[16];
  const float* dnbe = (const float*)d_in[17];
  const float* dew  = (const float*)d_in[18];
  const float* deb  = (const float*)d_in[19];
  const float* deg  = (const float*)d_in[20];
  const float* debe = (const float*)d_in[21];
  const float* cw1  = (const float*)d_in[22];
  const float* cb1  = (const float*)d_in[23];
  const float* cw2  = (const float*)d_in[24];
  const float* cb2  = (const float*)d_in[25];

  // ---- workspace layout: TOTAL 62,726,144 B = 59.8 MiB ----
  ushort_t* Zc = (ushort_t*)d_ws;            // bf16 Z state            27.56 MB
  ushort_t* Z1 = Zc + NZ_ELEM;               // bf16 pre-BN Z1          27.56 MB
  float*    fe = (float*)Z1;                 //   overlay: edge feats (Z1 dead when written)
  float*    H  = (float*)Z1;                 //   overlay: fc1 out     (fe dead when written)
  float*    Xc = (float*)(Z1 + NZ_ELEM);     // fp32 X state             1.43 MB
  float*    X1 = Xc + NX_ELEM;               // fp32 pre-BN X1           1.43 MB
  float*    fn = X1;                         //   overlay: node feats  (X1 dead when written)
  ushort_t* XZ = (ushort_t*)(X1 + NX_ELEM);  // bf16 features (B,2320)   4.75 MB
  float*    st = (float*)(XZ + BATCH*2320);  // stats: 2048 floats       8 KB
  float* zsum = st;        float* zsq = st + 464;
  float* xsum = st + 928;  float* xsq = st + 1392;
  float* dnS  = st + 1856; float* deS = st + 1866;

  float* outp = (float*)d_out;

  // init: Z fp32->bf16, X copy, zero stats
  k_initZ<<<2048, 256, 0, stream>>>((const float4*)Zin, (uint4*)Zc, NZ_ELEM / 8);
  k_initX<<<1392, 256, 0, stream>>>(Xin, Xc, NX_ELEM, st, 2048);

  // t = 0 snapshots
  k_dnode<<<464, 256, 0, stream>>>(Xc, dnw, dnb, fn, dnS, 0);
  k_dnode_apply<<<464, 256, 0, stream>>>(fn, dnS, dng, dnbe, XZ, 0);
  k_dedge<<<464, 256, 0, stream>>>(Zc, dew, deb, fe, deS, 0);
  k_dedge_apply<<<1392, 256, 0, stream>>>(fe, deS, deg, debe, XZ, 0);

  for (int i = 0; i < NL; i++){
    k_attn<<<BATCH, 1024, 0, stream>>>(Xc, Zc, Z1, X1, aw1, ab1, aw2, ab2,
                                       nw, nb, ew, eb, i);
    k_zstats<<<dim3(R, 16), 256, 0, stream>>>(Z1, zsum, zsq, i);
    k_xstats<<<R, 256, 0, stream>>>(X1, xsum, xsq, i);
    k_bnz<<<4096, 256, 0, stream>>>(Z1, Zc, zsum, zsq, geg, geb, i);
    k_bnx<<<1392, 256, 0, stream>>>(X1, Xc, xsum, xsq, gng, gnb, i);
    // fe/fn overlay Z1/X1: both are dead here (bnz/bnx consumed them)
    k_dedge<<<464, 256, 0, stream>>>(Zc, dew, deb, fe, deS, i + 1);
    k_dedge_apply<<<1392, 256, 0, stream>>>(fe, deS, deg, debe, XZ, i + 1);
    k_dnode<<<464, 256, 0, stream>>>(Xc, dnw, dnb, fn, dnS, i + 1);
    k_dnode_apply<<<464, 256, 0, stream>>>(fn, dnS, dng, dnbe, XZ, i + 1);
  }

  k_fc1<<<BATCH, 256, 0, stream>>>(XZ, cw1, cb1, H);
  k_fc2<<<BATCH, 256, 0, stream>>>(H, cw2, cb2, outp);
}

// Round 6
// 2343.360 us; speedup vs baseline: 6.0637x; 6.0637x over previous
//
#include <hip/hip_runtime.h>

#define R 116
#define BATCH 1024
#define NL 4
#define RR2 13456          // R*R
#define EPSF 1e-5f
#define NZ_ELEM (BATCH * RR2)     // 13,778,944
#define NX_ELEM (BATCH * R * 3)   //    356,352
#define LS 136                    // LDS row stride (bf16 elems): 272B, 16B-aligned, bank-skewed

typedef unsigned short ushort_t;
typedef __attribute__((ext_vector_type(8))) short bf16x8;
typedef __attribute__((ext_vector_type(4))) float f32x4;

__device__ __forceinline__ float bf2f(unsigned short u){
  union { unsigned int i; float f; } v; v.i = ((unsigned int)u) << 16; return v.f;
}
__device__ __forceinline__ unsigned short f2bf(float f){
  union { float ff; unsigned int i; } v; v.ff = f;
  return (unsigned short)((v.i + 0x7fffu + ((v.i >> 16) & 1u)) >> 16);
}
__device__ __forceinline__ float wsum(float v){
  #pragma unroll
  for (int o = 32; o > 0; o >>= 1) v += __shfl_xor(v, o, 64);
  return v;
}
__device__ __forceinline__ float wmaxr(float v){
  #pragma unroll
  for (int o = 32; o > 0; o >>= 1) v = fmaxf(v, __shfl_xor(v, o, 64));
  return v;
}

// ---------------- init: Z fp32 -> bf16 (8 elems/thread) ----------------
__global__ void k_initZ(const float4* __restrict__ src, uint4* __restrict__ dst, int n8){
  int idx = blockIdx.x * blockDim.x + threadIdx.x;
  int stride = gridDim.x * blockDim.x;
  for (int i = idx; i < n8; i += stride){
    float4 a = src[2*i], b = src[2*i+1];
    uint4 w;
    w.x = (unsigned)f2bf(a.x) | ((unsigned)f2bf(a.y) << 16);
    w.y = (unsigned)f2bf(a.z) | ((unsigned)f2bf(a.w) << 16);
    w.z = (unsigned)f2bf(b.x) | ((unsigned)f2bf(b.y) << 16);
    w.w = (unsigned)f2bf(b.z) | ((unsigned)f2bf(b.w) << 16);
    dst[i] = w;
  }
}

// ---------------- init: copy X fp32, zero stats ----------------
__global__ void k_initX(const float* __restrict__ src, float* __restrict__ dst, int n,
                        float* __restrict__ stats, int nstats){
  int idx = blockIdx.x * blockDim.x + threadIdx.x;
  int stride = gridDim.x * blockDim.x;
  for (int i = idx; i < n; i += stride) dst[i] = src[i];
  for (int i = idx; i < nstats; i += stride) stats[i] = 0.f;
}

// ---------------- init: pack weights for MFMA B-operand ----------------
// aw2p[l][c][k] = aw2[l][k][c]  (aw2^T, [n][k] layout for B-frag reads), 128x128 zero-pad, bf16
// ewp [l][e][c] = ew [l][e][c]  (ew row-major = (ew^T) in [n][k] layout), 128x128 zero-pad, bf16
__global__ void k_initW(const float* __restrict__ aw2, const float* __restrict__ ew,
                        ushort_t* __restrict__ aw2p, ushort_t* __restrict__ ewp){
  int idx = blockIdx.x * 256 + threadIdx.x;   // 4*128*128 = 65536 total
  int l = idx >> 14, rem = idx & 16383, row = rem >> 7, col = rem & 127;
  ushort_t v = 0, w = 0;
  if (row < R && col < R){
    v = f2bf(aw2[l*RR2 + col*R + row]);   // aw2[k=col][c=row]
    w = f2bf(ew [l*RR2 + row*R + col]);   // ew[e=row][c=col]
  }
  aw2p[idx] = v;
  ewp [idx] = w;
}

// ---------------- MFMA attention + edge/node update pre-BN ----------------
// Per graph b (one block, 16 waves):
//   P = softmax(K^T K) row-wise (bf16 in bA); ssm[n] = P[n,:].ab2
//   Stage A: W  = P  @ aw2            -> bB   (MFMA; B-frags from global aw2p)
//   Stage B: M  = Z  @ W^T  + ssm     -> bA   (MFMA; A=Zl, B=bB)
//   Stage C: T1 = M  @ Z              -> bB   (MFMA; A=bA, B=ZTl)
//   Stage D: Z1 = T1 @ ew^T + eb      -> glob (MFMA; A=bB, B-frags from global ewp)
//   X path : X1 = (M @ X) @ nw^T + nb        (VALU, tiny)
// MFMA layouts (HW-verified, cdna_hip_programming.md §3):
//   A-frag: lane holds A[m=lane&15][k=quad*8+i]  (8 contig bf16 = 1 ds_read_b128)
//   B-frag: lane holds B[k=quad*8+i][n=lane&15]  -> read row n of [n][k]-layout buffer
//   C/D   : col=lane&15, row=quad*4+reg
__launch_bounds__(1024)
__global__ void k_attn(const float* __restrict__ Xc, const ushort_t* __restrict__ Zc,
                       ushort_t* __restrict__ Z1, float* __restrict__ X1,
                       const float* __restrict__ aw1, const float* __restrict__ ab1,
                       const ushort_t* __restrict__ aw2p, const float* __restrict__ ab2,
                       const float* __restrict__ nw,  const float* __restrict__ nb,
                       const ushort_t* __restrict__ ewp,  const float* __restrict__ eb,
                       int layer)
{
  __shared__ ushort_t Zl [128*LS];   // Z row-major
  __shared__ ushort_t ZTl[128*LS];   // Z^T row-major
  __shared__ ushort_t bA [128*LS];   // P, then M
  __shared__ ushort_t bB [128*LS];   // W, then T1
  __shared__ float Ksm[3*R];
  __shared__ float ssm[R];

  const int b    = blockIdx.x;
  const int tid  = threadIdx.x;
  const int lane = tid & 63;
  const int wave = tid >> 6;          // 16 waves
  const int qm   = lane & 15;
  const int quad = lane >> 4;
  const int tr   = wave & 7;          // tile row 0..7
  const int tc0  = (wave >> 3) * 4;   // first tile col: 0 or 4

  const float*    Xb = Xc + (size_t)b * R * 3;
  const ushort_t* Zb = Zc + (size_t)b * RR2;
  const ushort_t* aw2l = aw2p + layer * 16384;
  const ushort_t* ewl  = ewp  + layer * 16384;
  const float* aw1l = aw1 + layer * 9;
  const float* ab1l = ab1 + layer * 3;
  const float* ab2l = ab2 + layer * R;
  const float* ebl  = eb  + layer * R;
  const float* nwl  = nw  + layer * 9;
  const float* nbl  = nb  + layer * 3;

  const f32x4 vzero = {0.f, 0.f, 0.f, 0.f};

  // phase 0: zero all LDS matrices (covers 128-pad regions)
  for (int i = tid; i < 128*LS/2; i += 1024){
    ((unsigned*)Zl)[i] = 0u; ((unsigned*)ZTl)[i] = 0u;
    ((unsigned*)bA)[i] = 0u; ((unsigned*)bB)[i] = 0u;
  }
  __syncthreads();

  // phase 1: stage Z and Z^T; compute K
  for (int e = tid; e < RR2; e += 1024){
    int rr = e / R, cc = e - rr*R;
    ushort_t z = Zb[e];
    Zl [rr*LS + cc] = z;
    ZTl[cc*LS + rr] = z;
  }
  if (tid < R){
    float x0 = Xb[tid*3+0], x1 = Xb[tid*3+1], x2 = Xb[tid*3+2];
    #pragma unroll
    for (int o = 0; o < 3; o++){
      Ksm[o*R + tid] = ab1l[o] + aw1l[o*3+0]*x0 + aw1l[o*3+1]*x1 + aw1l[o*3+2]*x2;
    }
  }
  __syncthreads();

  // phase 2: P rows (softmax) -> bA bf16 ; ssm[n] = P[n,:].ab2
  for (int n = wave; n < R; n += 16){
    float k0 = Ksm[n], k1 = Ksm[R+n], k2 = Ksm[2*R+n];
    int m0 = lane, m1 = lane + 64;
    float a0 = k0*Ksm[m0] + k1*Ksm[R+m0] + k2*Ksm[2*R+m0];
    float a1 = (m1 < R) ? (k0*Ksm[m1] + k1*Ksm[R+m1] + k2*Ksm[2*R+m1]) : -1e30f;
    float mx = wmaxr(fmaxf(a0, a1));
    float e0 = __expf(a0 - mx);
    float e1 = (m1 < R) ? __expf(a1 - mx) : 0.f;
    float sm = wsum(e0 + e1);
    float sab = wsum(e0 * ab2l[m0] + ((m1 < R) ? e1 * ab2l[m1] : 0.f));
    float inv = 1.f / sm;
    bA[n*LS + m0] = f2bf(e0 * inv);
    if (m1 < R) bA[n*LS + m1] = f2bf(e1 * inv);
    if (lane == 0) ssm[n] = sab * inv;
  }
  __syncthreads();

  // ---- Stage A: W = P @ aw2 -> bB ----
  {
    f32x4 acc[4];
    #pragma unroll
    for (int t = 0; t < 4; t++) acc[t] = vzero;
    for (int kk = 0; kk < 128; kk += 32){
      bf16x8 a = *(const bf16x8*)&bA[(tr*16 + qm)*LS + kk + quad*8];
      #pragma unroll
      for (int t = 0; t < 4; t++){
        int n = (tc0 + t)*16 + qm;
        bf16x8 bf = *(const bf16x8*)(aw2l + n*128 + kk + quad*8);
        acc[t] = __builtin_amdgcn_mfma_f32_16x16x32_bf16(a, bf, acc[t], 0, 0, 0);
      }
    }
    #pragma unroll
    for (int t = 0; t < 4; t++){
      int n = (tc0 + t)*16 + qm;
      #pragma unroll
      for (int rg = 0; rg < 4; rg++)
        bB[(tr*16 + quad*4 + rg)*LS + n] = f2bf(acc[t][rg]);
    }
  }
  __syncthreads();

  // ---- Stage B: M = Z @ W^T + ssm -> bA ----
  {
    f32x4 acc[4];
    #pragma unroll
    for (int t = 0; t < 4; t++) acc[t] = vzero;
    for (int kk = 0; kk < 128; kk += 32){
      bf16x8 a = *(const bf16x8*)&Zl[(tr*16 + qm)*LS + kk + quad*8];
      #pragma unroll
      for (int t = 0; t < 4; t++){
        int n = (tc0 + t)*16 + qm;
        bf16x8 bf = *(const bf16x8*)&bB[n*LS + kk + quad*8];
        acc[t] = __builtin_amdgcn_mfma_f32_16x16x32_bf16(a, bf, acc[t], 0, 0, 0);
      }
    }
    #pragma unroll
    for (int t = 0; t < 4; t++){
      int n = (tc0 + t)*16 + qm;
      float sadd = (n < R) ? ssm[n] : 0.f;
      #pragma unroll
      for (int rg = 0; rg < 4; rg++)
        bA[(tr*16 + quad*4 + rg)*LS + n] = f2bf(acc[t][rg] + sadd);
    }
  }
  __syncthreads();

  // ---- Stage C: T1 = M @ Z -> bB ----
  {
    f32x4 acc[4];
    #pragma unroll
    for (int t = 0; t < 4; t++) acc[t] = vzero;
    for (int kk = 0; kk < 128; kk += 32){
      bf16x8 a = *(const bf16x8*)&bA[(tr*16 + qm)*LS + kk + quad*8];
      #pragma unroll
      for (int t = 0; t < 4; t++){
        int n = (tc0 + t)*16 + qm;
        bf16x8 bf = *(const bf16x8*)&ZTl[n*LS + kk + quad*8];
        acc[t] = __builtin_amdgcn_mfma_f32_16x16x32_bf16(a, bf, acc[t], 0, 0, 0);
      }
    }
    #pragma unroll
    for (int t = 0; t < 4; t++){
      int n = (tc0 + t)*16 + qm;
      #pragma unroll
      for (int rg = 0; rg < 4; rg++)
        bB[(tr*16 + quad*4 + rg)*LS + n] = f2bf(acc[t][rg]);
    }
  }
  __syncthreads();

  // ---- Stage D: Z1 = T1 @ ew^T + eb -> global bf16 ----
  {
    f32x4 acc[4];
    #pragma unroll
    for (int t = 0; t < 4; t++) acc[t] = vzero;
    for (int kk = 0; kk < 128; kk += 32){
      bf16x8 a = *(const bf16x8*)&bB[(tr*16 + qm)*LS + kk + quad*8];
      #pragma unroll
      for (int t = 0; t < 4; t++){
        int n = (tc0 + t)*16 + qm;
        bf16x8 bf = *(const bf16x8*)(ewl + n*128 + kk + quad*8);
        acc[t] = __builtin_amdgcn_mfma_f32_16x16x32_bf16(a, bf, acc[t], 0, 0, 0);
      }
    }
    #pragma unroll
    for (int t = 0; t < 4; t++){
      int col = (tc0 + t)*16 + qm;
      if (col < R){
        float bias = ebl[col];
        #pragma unroll
        for (int rg = 0; rg < 4; rg++){
          int row = tr*16 + quad*4 + rg;
          if (row < R)
            Z1[(size_t)b*RR2 + row*R + col] = f2bf(acc[t][rg] + bias);
        }
      }
    }
  }

  // ---- X path: T1x = M @ X ; X1 = T1x @ nw^T + nb (M stable in bA) ----
  for (int n = wave; n < R; n += 16){
    float t0 = 0.f, t1 = 0.f, t2 = 0.f;
    for (int m = lane; m < R; m += 64){
      float p = bf2f(bA[n*LS + m]);
      const float* xr = Xb + m * 3;
      t0 += p * xr[0]; t1 += p * xr[1]; t2 += p * xr[2];
    }
    t0 = wsum(t0); t1 = wsum(t1); t2 = wsum(t2);
    if (lane < 3){
      int e = lane;
      float v = nbl[e] + t0*nwl[e*3+0] + t1*nwl[e*3+1] + t2*nwl[e*3+2];
      X1[((size_t)b*R + n)*3 + e] = v;
    }
  }
}

// ---------------- BN stats for Z1: per-channel n, over (b, c) ----------------
__global__ void k_zstats(const ushort_t* __restrict__ Z1, float* __restrict__ zsum,
                         float* __restrict__ zsq, int layer){
  int n = blockIdx.x;           // 0..115
  int s = blockIdx.y;           // 0..15 batch slice of 64
  int tid = threadIdx.x;
  float sum = 0.f, sq = 0.f;
  for (int idx = tid; idx < 64 * R; idx += 256){
    int bl = idx / R;
    int c  = idx - bl * R;
    float v = bf2f(Z1[((size_t)(s*64 + bl) * R + n) * R + c]);
    sum += v; sq += v * v;
  }
  sum = wsum(sum); sq = wsum(sq);
  __shared__ float s1[4], s2[4];
  int lane = tid & 63, wave = tid >> 6;
  if (lane == 0){ s1[wave] = sum; s2[wave] = sq; }
  __syncthreads();
  if (tid == 0){
    atomicAdd(&zsum[layer*R + n], s1[0]+s1[1]+s1[2]+s1[3]);
    atomicAdd(&zsq [layer*R + n], s2[0]+s2[1]+s2[2]+s2[3]);
  }
}

// ---------------- BN stats for X1 ----------------
__global__ void k_xstats(const float* __restrict__ X1, float* __restrict__ xsum,
                         float* __restrict__ xsq, int layer){
  int n = blockIdx.x;
  int tid = threadIdx.x;
  float sum = 0.f, sq = 0.f;
  for (int idx = tid; idx < BATCH * 3; idx += 256){
    int bl = idx / 3, c = idx - bl * 3;
    float v = X1[((size_t)bl * R + n) * 3 + c];
    sum += v; sq += v * v;
  }
  sum = wsum(sum); sq = wsum(sq);
  __shared__ float s1[4], s2[4];
  int lane = tid & 63, wave = tid >> 6;
  if (lane == 0){ s1[wave] = sum; s2[wave] = sq; }
  __syncthreads();
  if (tid == 0){
    xsum[layer*R + n] = s1[0]+s1[1]+s1[2]+s1[3];
    xsq [layer*R + n] = s2[0]+s2[1]+s2[2]+s2[3];
  }
}

// ---------------- apply BN+relu+residual to Z (bf16 in/out) ----------------
__global__ void k_bnz(const ushort_t* __restrict__ Z1, ushort_t* __restrict__ Zc,
                      const float* __restrict__ zsum, const float* __restrict__ zsq,
                      const float* __restrict__ geg, const float* __restrict__ geb,
                      int layer){
  const float cnt = (float)(BATCH * R);
  int i = blockIdx.x * blockDim.x + threadIdx.x;
  int stride = gridDim.x * blockDim.x;
  for (int idx = i; idx < BATCH * RR2; idx += stride){
    int n = (idx / R) % R;
    float m = zsum[layer*R + n] / cnt;
    float v = fmaxf(zsq[layer*R + n] / cnt - m * m, 0.f);
    float rs = rsqrtf(v + EPSF);
    float val = (bf2f(Z1[idx]) - m) * rs * geg[layer*R + n] + geb[layer*R + n];
    Zc[idx] = f2bf(fmaxf(val, 0.f) + bf2f(Zc[idx]));
  }
}

__global__ void k_bnx(const float* __restrict__ X1, float* __restrict__ Xc,
                      const float* __restrict__ xsum, const float* __restrict__ xsq,
                      const float* __restrict__ gng, const float* __restrict__ gnb,
                      int layer){
  const float cnt = (float)(BATCH * 3);
  int idx = blockIdx.x * blockDim.x + threadIdx.x;   // exactly BATCH*R*3 threads
  if (idx >= BATCH * R * 3) return;
  int n = (idx / 3) % R;
  float m = xsum[layer*R + n] / cnt;
  float v = fmaxf(xsq[layer*R + n] / cnt - m * m, 0.f);
  float rs = rsqrtf(v + EPSF);
  float val = (X1[idx] - m) * rs * gng[layer*R + n] + gnb[layer*R + n];
  Xc[idx] = fmaxf(val, 0.f) + Xc[idx];
}

// ---------------- down-sample node ----------------
__global__ void k_dnode(const float* __restrict__ Xc, const float* __restrict__ dnw,
                        const float* __restrict__ dnb, float* __restrict__ fn,
                        float* __restrict__ dnS, int t){
  int idx = blockIdx.x * 256 + threadIdx.x;    // exactly BATCH*R
  float w0 = dnw[t*3+0], w1 = dnw[t*3+1], w2 = dnw[t*3+2];
  float bb = dnb[t];
  const float* x = Xc + (size_t)idx * 3;
  float f = fmaxf(w0*x[0] + w1*x[1] + w2*x[2] + bb, 0.f);
  fn[idx] = f;
  float s = wsum(f), q = wsum(f * f);
  __shared__ float s1[4], s2[4];
  int lane = threadIdx.x & 63, wave = threadIdx.x >> 6;
  if (lane == 0){ s1[wave] = s; s2[wave] = q; }
  __syncthreads();
  if (threadIdx.x == 0){
    atomicAdd(&dnS[t*2+0], s1[0]+s1[1]+s1[2]+s1[3]);
    atomicAdd(&dnS[t*2+1], s2[0]+s2[1]+s2[2]+s2[3]);
  }
}

__global__ void k_dnode_apply(const float* __restrict__ fn, const float* __restrict__ dnS,
                              const float* __restrict__ dng, const float* __restrict__ dnbe,
                              ushort_t* __restrict__ XZ, int t){
  int idx = blockIdx.x * 256 + threadIdx.x;    // BATCH*R
  const float cnt = (float)(BATCH * R);
  float m = dnS[t*2+0] / cnt;
  float v = fmaxf(dnS[t*2+1] / cnt - m * m, 0.f);
  float h = (fn[idx] - m) * rsqrtf(v + EPSF) * dng[t] + dnbe[t];
  int bi = idx / R, r = idx - bi * R;
  XZ[(size_t)bi * 2320 + t*R + r] = f2bf(h);
}

// ---------------- down-sample edge ----------------
__global__ void k_dedge(const ushort_t* __restrict__ Zc, const float* __restrict__ dew,
                        const float* __restrict__ deb, float* __restrict__ fe,
                        float* __restrict__ deS, int t){
  __shared__ float wsm[78];
  if (threadIdx.x < 78) wsm[threadIdx.x] = dew[t*78 + threadIdx.x];
  __syncthreads();
  int idx = blockIdx.x * 256 + threadIdx.x;    // BATCH*R rows
  const ushort_t* x = Zc + (size_t)idx * R;
  float bb = deb[t];
  float f0 = 0.f, f1 = 0.f, f2 = 0.f;
  for (int j = 0; j < 78; j++){
    float w = wsm[j];
    if (j >= 39) f0 += w * bf2f(x[j - 39]);
    f1 += w * bf2f(x[j]);
    if (j < 77)  f2 += w * bf2f(x[j + 39]);
  }
  f0 = fmaxf(f0 + bb, 0.f); f1 = fmaxf(f1 + bb, 0.f); f2 = fmaxf(f2 + bb, 0.f);
  fe[(size_t)idx*3 + 0] = f0; fe[(size_t)idx*3 + 1] = f1; fe[(size_t)idx*3 + 2] = f2;
  float s = wsum(f0 + f1 + f2), q = wsum(f0*f0 + f1*f1 + f2*f2);
  __shared__ float s1[4], s2[4];
  int lane = threadIdx.x & 63, wave = threadIdx.x >> 6;
  if (lane == 0){ s1[wave] = s; s2[wave] = q; }
  __syncthreads();
  if (threadIdx.x == 0){
    atomicAdd(&deS[t*2+0], s1[0]+s1[1]+s1[2]+s1[3]);
    atomicAdd(&deS[t*2+1], s2[0]+s2[1]+s2[2]+s2[3]);
  }
}

__global__ void k_dedge_apply(const float* __restrict__ fe, const float* __restrict__ deS,
                              const float* __restrict__ deg, const float* __restrict__ debe,
                              ushort_t* __restrict__ XZ, int t){
  int idx = blockIdx.x * 256 + threadIdx.x;    // BATCH*R*3
  const float cnt = (float)(BATCH * R * 3);
  float m = deS[t*2+0] / cnt;
  float v = fmaxf(deS[t*2+1] / cnt - m * m, 0.f);
  float h = (fe[idx] - m) * rsqrtf(v + EPSF) * deg[t] + debe[t];
  int bi = idx / (R * 3), rem = idx - bi * (R * 3);
  XZ[(size_t)bi * 2320 + 5*R + t*3*R + rem] = f2bf(h);
}

// ---------------- classifier ----------------
__launch_bounds__(256)
__global__ void k_fc1(const ushort_t* __restrict__ XZ, const float* __restrict__ cw1,
                      const float* __restrict__ cb1, float* __restrict__ H){
  __shared__ __align__(16) float xz[2320];
  int b = blockIdx.x, tid = threadIdx.x;
  for (int k = tid; k < 2320; k += 256) xz[k] = bf2f(XZ[(size_t)b * 2320 + k]);
  __syncthreads();
  const float4* xzv = (const float4*)xz;   // 580 vec4
  #pragma unroll
  for (int q = 0; q < 4; q++){
    int j = tid + 256 * q;
    const float4* wr = (const float4*)(cw1 + (size_t)j * 2320);
    float acc = cb1[j];
    #pragma unroll 4
    for (int kk = 0; kk < 580; kk++){
      float4 w4 = wr[kk];
      float4 x4 = xzv[kk];
      acc += w4.x*x4.x + w4.y*x4.y + w4.z*x4.z + w4.w*x4.w;
    }
    H[(size_t)b * 1024 + j] = fmaxf(acc, 0.f);
  }
}

__global__ void k_fc2(const float* __restrict__ H, const float* __restrict__ cw2,
                      const float* __restrict__ cb2, float* __restrict__ out){
  int b = blockIdx.x, tid = threadIdx.x;
  float a0 = 0.f, a1 = 0.f;
  for (int j = tid; j < 1024; j += 256){
    float h = H[(size_t)b * 1024 + j];
    a0 += h * cw2[j];
    a1 += h * cw2[1024 + j];
  }
  a0 = wsum(a0); a1 = wsum(a1);
  __shared__ float s0[4], s1[4];
  int lane = tid & 63, wave = tid >> 6;
  if (lane == 0){ s0[wave] = a0; s1[wave] = a1; }
  __syncthreads();
  if (tid == 0){
    out[b*2 + 0] = s0[0]+s0[1]+s0[2]+s0[3] + cb2[0];   // fp32 output (reference dtype)
    out[b*2 + 1] = s1[0]+s1[1]+s1[2]+s1[3] + cb2[1];
  }
}

extern "C" void kernel_launch(void* const* d_in, const int* in_sizes, int n_in,
                              void* d_out, int out_size, void* d_ws, size_t ws_size,
                              hipStream_t stream)
{
  const float* Xin  = (const float*)d_in[0];
  const float* Zin  = (const float*)d_in[1];
  const float* aw1  = (const float*)d_in[2];
  const float* ab1  = (const float*)d_in[3];
  const float* aw2  = (const float*)d_in[4];
  const float* ab2  = (const float*)d_in[5];
  const float* nw   = (const float*)d_in[6];
  const float* nb   = (const float*)d_in[7];
  const float* ew   = (const float*)d_in[8];
  const float* eb   = (const float*)d_in[9];
  const float* gng  = (const float*)d_in[10];
  const float* gnb  = (const float*)d_in[11];
  const float* geg  = (const float*)d_in[12];
  const float* geb  = (const float*)d_in[13];
  const float* dnw  = (const float*)d_in[14];
  const float* dnb  = (const float*)d_in[15];
  const float* dng  = (const float*)d_in[16];
  const float* dnbe = (const float*)d_in[17];
  const float* dew  = (const float*)d_in[18];
  const float* deb  = (const float*)d_in[19];
  const float* deg  = (const float*)d_in[20];
  const float* debe = (const float*)d_in[21];
  const float* cw1  = (const float*)d_in[22];
  const float* cb1  = (const float*)d_in[23];
  const float* cw2  = (const float*)d_in[24];
  const float* cb2  = (const float*)d_in[25];

  // ---- workspace layout: TOTAL ~60.1 MiB ----
  ushort_t* Zc = (ushort_t*)d_ws;            // bf16 Z state            27.56 MB
  ushort_t* Z1 = Zc + NZ_ELEM;               // bf16 pre-BN Z1          27.56 MB
  float*    fe = (float*)Z1;                 //   overlay: edge feats (Z1 dead when written)
  float*    H  = (float*)Z1;                 //   overlay: fc1 out     (fe dead when written)
  float*    Xc = (float*)(Z1 + NZ_ELEM);     // fp32 X state             1.43 MB
  float*    X1 = Xc + NX_ELEM;               // fp32 pre-BN X1           1.43 MB
  float*    fn = X1;                         //   overlay: node feats  (X1 dead when written)
  ushort_t* XZ = (ushort_t*)(X1 + NX_ELEM);  // bf16 features (B,2320)   4.75 MB
  float*    st = (float*)(XZ + BATCH*2320);  // stats: 2048 floats       8 KB
  ushort_t* aw2p = (ushort_t*)(st + 2048);   // bf16 aw2^T padded 4x128x128  128 KB
  ushort_t* ewp  = aw2p + 4*16384;           // bf16 ew    padded 4x128x128  128 KB
  float* zsum = st;        float* zsq = st + 464;
  float* xsum = st + 928;  float* xsq = st + 1392;
  float* dnS  = st + 1856; float* deS = st + 1866;

  float* outp = (float*)d_out;

  // init: Z fp32->bf16, X copy, zero stats, pack MFMA weights
  k_initZ<<<2048, 256, 0, stream>>>((const float4*)Zin, (uint4*)Zc, NZ_ELEM / 8);
  k_initX<<<1392, 256, 0, stream>>>(Xin, Xc, NX_ELEM, st, 2048);
  k_initW<<<256, 256, 0, stream>>>(aw2, ew, aw2p, ewp);

  // t = 0 snapshots
  k_dnode<<<464, 256, 0, stream>>>(Xc, dnw, dnb, fn, dnS, 0);
  k_dnode_apply<<<464, 256, 0, stream>>>(fn, dnS, dng, dnbe, XZ, 0);
  k_dedge<<<464, 256, 0, stream>>>(Zc, dew, deb, fe, deS, 0);
  k_dedge_apply<<<1392, 256, 0, stream>>>(fe, deS, deg, debe, XZ, 0);

  for (int i = 0; i < NL; i++){
    k_attn<<<BATCH, 1024, 0, stream>>>(Xc, Zc, Z1, X1, aw1, ab1, aw2p, ab2,
                                       nw, nb, ewp, eb, i);
    k_zstats<<<dim3(R, 16), 256, 0, stream>>>(Z1, zsum, zsq, i);
    k_xstats<<<R, 256, 0, stream>>>(X1, xsum, xsq, i);
    k_bnz<<<4096, 256, 0, stream>>>(Z1, Zc, zsum, zsq, geg, geb, i);
    k_bnx<<<1392, 256, 0, stream>>>(X1, Xc, xsum, xsq, gng, gnb, i);
    // fe/fn overlay Z1/X1: both are dead here (bnz/bnx consumed them)
    k_dedge<<<464, 256, 0, stream>>>(Zc, dew, deb, fe, deS, i + 1);
    k_dedge_apply<<<1392, 256, 0, stream>>>(fe, deS, deg, debe, XZ, i + 1);
    k_dnode<<<464, 256, 0, stream>>>(Xc, dnw, dnb, fn, dnS, i + 1);
    k_dnode_apply<<<464, 256, 0, stream>>>(fn, dnS, dng, dnbe, XZ, i + 1);
  }

  k_fc1<<<BATCH, 256, 0, stream>>>(XZ, cw1, cb1, H);
  k_fc2<<<BATCH, 256, 0, stream>>>(H, cw2, cb2, outp);
}

// Round 7
// 1547.305 us; speedup vs baseline: 9.1833x; 1.5145x over previous
//
#include <hip/hip_runtime.h>

#define R 116
#define BATCH 1024
#define NL 4
#define RR2 13456          // R*R
#define EPSF 1e-5f
#define NZ_ELEM (BATCH * RR2)     // 13,778,944
#define NX_ELEM (BATCH * R * 3)   //    356,352
#define LS 136                    // LDS row stride (bf16 elems)
#define XZS 2336                  // XZ/cw1p K-stride: 2320 padded to 73*32

typedef unsigned short ushort_t;
typedef __attribute__((ext_vector_type(8))) short bf16x8;
typedef __attribute__((ext_vector_type(4))) float f32x4;

__device__ __forceinline__ float bf2f(unsigned short u){
  union { unsigned int i; float f; } v; v.i = ((unsigned int)u) << 16; return v.f;
}
__device__ __forceinline__ unsigned short f2bf(float f){
  union { float ff; unsigned int i; } v; v.ff = f;
  return (unsigned short)((v.i + 0x7fffu + ((v.i >> 16) & 1u)) >> 16);
}
__device__ __forceinline__ float wsum(float v){
  #pragma unroll
  for (int o = 32; o > 0; o >>= 1) v += __shfl_xor(v, o, 64);
  return v;
}
__device__ __forceinline__ float wmaxr(float v){
  #pragma unroll
  for (int o = 32; o > 0; o >>= 1) v = fmaxf(v, __shfl_xor(v, o, 64));
  return v;
}

// ---------------- init: Z fp32 -> bf16 (8 elems/thread) ----------------
__global__ void k_initZ(const float4* __restrict__ src, uint4* __restrict__ dst, int n8){
  int idx = blockIdx.x * blockDim.x + threadIdx.x;
  int stride = gridDim.x * blockDim.x;
  for (int i = idx; i < n8; i += stride){
    float4 a = src[2*i], b = src[2*i+1];
    uint4 w;
    w.x = (unsigned)f2bf(a.x) | ((unsigned)f2bf(a.y) << 16);
    w.y = (unsigned)f2bf(a.z) | ((unsigned)f2bf(a.w) << 16);
    w.z = (unsigned)f2bf(b.x) | ((unsigned)f2bf(b.y) << 16);
    w.w = (unsigned)f2bf(b.z) | ((unsigned)f2bf(b.w) << 16);
    dst[i] = w;
  }
}

// ---------------- init: copy X fp32, zero stats, zero XZ (incl. K-pad) ----------------
__global__ void k_initX(const float* __restrict__ src, float* __restrict__ dst, int n,
                        float* __restrict__ stats, int nstats,
                        unsigned* __restrict__ xzw, int nxzw){
  int idx = blockIdx.x * blockDim.x + threadIdx.x;
  int stride = gridDim.x * blockDim.x;
  for (int i = idx; i < n; i += stride) dst[i] = src[i];
  for (int i = idx; i < nstats; i += stride) stats[i] = 0.f;
  for (int i = idx; i < nxzw; i += stride) xzw[i] = 0u;
}

// ---------------- init: pack aw2^T / ew for MFMA B-operand (128x128, bf16) ----------------
__global__ void k_initW(const float* __restrict__ aw2, const float* __restrict__ ew,
                        ushort_t* __restrict__ aw2p, ushort_t* __restrict__ ewp){
  int idx = blockIdx.x * 256 + threadIdx.x;   // 4*128*128 = 65536 total
  int l = idx >> 14, rem = idx & 16383, row = rem >> 7, col = rem & 127;
  ushort_t v = 0, w = 0;
  if (row < R && col < R){
    v = f2bf(aw2[l*RR2 + col*R + row]);   // aw2[k=col][c=row]
    w = f2bf(ew [l*RR2 + row*R + col]);   // ew[e=row][c=col]
  }
  aw2p[idx] = v;
  ewp [idx] = w;
}

// ---------------- init: pack cw1 -> bf16 [n][k] with K padded to XZS ----------------
__global__ void k_initC(const float* __restrict__ cw1, ushort_t* __restrict__ cw1p){
  int idx = blockIdx.x * 256 + threadIdx.x;   // 1024*XZS
  if (idx >= 1024 * XZS) return;
  int n = idx / XZS, k = idx - n * XZS;
  cw1p[idx] = (k < 2320) ? f2bf(cw1[n*2320 + k]) : (ushort_t)0;
}

// ---------------- MFMA attention + edge/node update pre-BN ----------------
// MFMA layouts (HW-verified): A-frag lane = A[m=lane&15][k=quad*8+i];
// B-frag lane = B[k=quad*8+i][n=lane&15] (row n of [n][k] buffer);
// C/D: col=lane&15, row=quad*4+reg.
__launch_bounds__(1024)
__global__ void k_attn(const float* __restrict__ Xc, const ushort_t* __restrict__ Zc,
                       ushort_t* __restrict__ Z1, float* __restrict__ X1,
                       const float* __restrict__ aw1, const float* __restrict__ ab1,
                       const ushort_t* __restrict__ aw2p, const float* __restrict__ ab2,
                       const float* __restrict__ nw,  const float* __restrict__ nb,
                       const ushort_t* __restrict__ ewp,  const float* __restrict__ eb,
                       int layer)
{
  __shared__ ushort_t Zl [128*LS];   // Z row-major
  __shared__ ushort_t ZTl[128*LS];   // Z^T row-major
  __shared__ ushort_t bA [128*LS];   // P, then M
  __shared__ ushort_t bB [128*LS];   // W, then T1
  __shared__ float Ksm[3*R];
  __shared__ float ssm[R];

  const int b    = blockIdx.x;
  const int tid  = threadIdx.x;
  const int lane = tid & 63;
  const int wave = tid >> 6;          // 16 waves
  const int qm   = lane & 15;
  const int quad = lane >> 4;
  const int tr   = wave & 7;          // tile row 0..7
  const int tc0  = (wave >> 3) * 4;   // first tile col: 0 or 4

  const float*    Xb = Xc + (size_t)b * R * 3;
  const ushort_t* Zb = Zc + (size_t)b * RR2;
  const ushort_t* aw2l = aw2p + layer * 16384;
  const ushort_t* ewl  = ewp  + layer * 16384;
  const float* aw1l = aw1 + layer * 9;
  const float* ab1l = ab1 + layer * 3;
  const float* ab2l = ab2 + layer * R;
  const float* ebl  = eb  + layer * R;
  const float* nwl  = nw  + layer * 9;
  const float* nbl  = nb  + layer * 3;

  const f32x4 vzero = {0.f, 0.f, 0.f, 0.f};

  // phase 0: zero all LDS matrices (covers 128-pad regions)
  for (int i = tid; i < 128*LS/2; i += 1024){
    ((unsigned*)Zl)[i] = 0u; ((unsigned*)ZTl)[i] = 0u;
    ((unsigned*)bA)[i] = 0u; ((unsigned*)bB)[i] = 0u;
  }
  __syncthreads();

  // phase 1: stage Z and Z^T; compute K
  for (int e = tid; e < RR2; e += 1024){
    int rr = e / R, cc = e - rr*R;
    ushort_t z = Zb[e];
    Zl [rr*LS + cc] = z;
    ZTl[cc*LS + rr] = z;
  }
  if (tid < R){
    float x0 = Xb[tid*3+0], x1 = Xb[tid*3+1], x2 = Xb[tid*3+2];
    #pragma unroll
    for (int o = 0; o < 3; o++){
      Ksm[o*R + tid] = ab1l[o] + aw1l[o*3+0]*x0 + aw1l[o*3+1]*x1 + aw1l[o*3+2]*x2;
    }
  }
  __syncthreads();

  // phase 2: P rows (softmax) -> bA bf16 ; ssm[n] = P[n,:].ab2
  for (int n = wave; n < R; n += 16){
    float k0 = Ksm[n], k1 = Ksm[R+n], k2 = Ksm[2*R+n];
    int m0 = lane, m1 = lane + 64;
    float a0 = k0*Ksm[m0] + k1*Ksm[R+m0] + k2*Ksm[2*R+m0];
    float a1 = (m1 < R) ? (k0*Ksm[m1] + k1*Ksm[R+m1] + k2*Ksm[2*R+m1]) : -1e30f;
    float mx = wmaxr(fmaxf(a0, a1));
    float e0 = __expf(a0 - mx);
    float e1 = (m1 < R) ? __expf(a1 - mx) : 0.f;
    float sm = wsum(e0 + e1);
    float sab = wsum(e0 * ab2l[m0] + ((m1 < R) ? e1 * ab2l[m1] : 0.f));
    float inv = 1.f / sm;
    bA[n*LS + m0] = f2bf(e0 * inv);
    if (m1 < R) bA[n*LS + m1] = f2bf(e1 * inv);
    if (lane == 0) ssm[n] = sab * inv;
  }
  __syncthreads();

  // ---- Stage A: W = P @ aw2 -> bB ----
  {
    f32x4 acc[4];
    #pragma unroll
    for (int t = 0; t < 4; t++) acc[t] = vzero;
    for (int kk = 0; kk < 128; kk += 32){
      bf16x8 a = *(const bf16x8*)&bA[(tr*16 + qm)*LS + kk + quad*8];
      #pragma unroll
      for (int t = 0; t < 4; t++){
        int n = (tc0 + t)*16 + qm;
        bf16x8 bf = *(const bf16x8*)(aw2l + n*128 + kk + quad*8);
        acc[t] = __builtin_amdgcn_mfma_f32_16x16x32_bf16(a, bf, acc[t], 0, 0, 0);
      }
    }
    #pragma unroll
    for (int t = 0; t < 4; t++){
      int n = (tc0 + t)*16 + qm;
      #pragma unroll
      for (int rg = 0; rg < 4; rg++)
        bB[(tr*16 + quad*4 + rg)*LS + n] = f2bf(acc[t][rg]);
    }
  }
  __syncthreads();

  // ---- Stage B: M = Z @ W^T + ssm -> bA ----
  {
    f32x4 acc[4];
    #pragma unroll
    for (int t = 0; t < 4; t++) acc[t] = vzero;
    for (int kk = 0; kk < 128; kk += 32){
      bf16x8 a = *(const bf16x8*)&Zl[(tr*16 + qm)*LS + kk + quad*8];
      #pragma unroll
      for (int t = 0; t < 4; t++){
        int n = (tc0 + t)*16 + qm;
        bf16x8 bf = *(const bf16x8*)&bB[n*LS + kk + quad*8];
        acc[t] = __builtin_amdgcn_mfma_f32_16x16x32_bf16(a, bf, acc[t], 0, 0, 0);
      }
    }
    #pragma unroll
    for (int t = 0; t < 4; t++){
      int n = (tc0 + t)*16 + qm;
      float sadd = (n < R) ? ssm[n] : 0.f;
      #pragma unroll
      for (int rg = 0; rg < 4; rg++)
        bA[(tr*16 + quad*4 + rg)*LS + n] = f2bf(acc[t][rg] + sadd);
    }
  }
  __syncthreads();

  // ---- Stage C: T1 = M @ Z -> bB ----
  {
    f32x4 acc[4];
    #pragma unroll
    for (int t = 0; t < 4; t++) acc[t] = vzero;
    for (int kk = 0; kk < 128; kk += 32){
      bf16x8 a = *(const bf16x8*)&bA[(tr*16 + qm)*LS + kk + quad*8];
      #pragma unroll
      for (int t = 0; t < 4; t++){
        int n = (tc0 + t)*16 + qm;
        bf16x8 bf = *(const bf16x8*)&ZTl[n*LS + kk + quad*8];
        acc[t] = __builtin_amdgcn_mfma_f32_16x16x32_bf16(a, bf, acc[t], 0, 0, 0);
      }
    }
    #pragma unroll
    for (int t = 0; t < 4; t++){
      int n = (tc0 + t)*16 + qm;
      #pragma unroll
      for (int rg = 0; rg < 4; rg++)
        bB[(tr*16 + quad*4 + rg)*LS + n] = f2bf(acc[t][rg]);
    }
  }
  __syncthreads();

  // ---- Stage D: Z1 = T1 @ ew^T + eb -> global bf16 ----
  {
    f32x4 acc[4];
    #pragma unroll
    for (int t = 0; t < 4; t++) acc[t] = vzero;
    for (int kk = 0; kk < 128; kk += 32){
      bf16x8 a = *(const bf16x8*)&bB[(tr*16 + qm)*LS + kk + quad*8];
      #pragma unroll
      for (int t = 0; t < 4; t++){
        int n = (tc0 + t)*16 + qm;
        bf16x8 bf = *(const bf16x8*)(ewl + n*128 + kk + quad*8);
        acc[t] = __builtin_amdgcn_mfma_f32_16x16x32_bf16(a, bf, acc[t], 0, 0, 0);
      }
    }
    #pragma unroll
    for (int t = 0; t < 4; t++){
      int col = (tc0 + t)*16 + qm;
      if (col < R){
        float bias = ebl[col];
        #pragma unroll
        for (int rg = 0; rg < 4; rg++){
          int row = tr*16 + quad*4 + rg;
          if (row < R)
            Z1[(size_t)b*RR2 + row*R + col] = f2bf(acc[t][rg] + bias);
        }
      }
    }
  }

  // ---- X path: T1x = M @ X ; X1 = T1x @ nw^T + nb (M stable in bA) ----
  for (int n = wave; n < R; n += 16){
    float t0 = 0.f, t1 = 0.f, t2 = 0.f;
    for (int m = lane; m < R; m += 64){
      float p = bf2f(bA[n*LS + m]);
      const float* xr = Xb + m * 3;
      t0 += p * xr[0]; t1 += p * xr[1]; t2 += p * xr[2];
    }
    t0 = wsum(t0); t1 = wsum(t1); t2 = wsum(t2);
    if (lane < 3){
      int e = lane;
      float v = nbl[e] + t0*nwl[e*3+0] + t1*nwl[e*3+1] + t2*nwl[e*3+2];
      X1[((size_t)b*R + n)*3 + e] = v;
    }
  }
}

// ---------------- BN stats for Z1: per-channel n, over (b, c) ----------------
__global__ void k_zstats(const ushort_t* __restrict__ Z1, float* __restrict__ zsum,
                         float* __restrict__ zsq, int layer){
  int n = blockIdx.x;           // 0..115
  int s = blockIdx.y;           // 0..15 batch slice of 64
  int tid = threadIdx.x;
  float sum = 0.f, sq = 0.f;
  for (int idx = tid; idx < 64 * R; idx += 256){
    int bl = idx / R;
    int c  = idx - bl * R;
    float v = bf2f(Z1[((size_t)(s*64 + bl) * R + n) * R + c]);
    sum += v; sq += v * v;
  }
  sum = wsum(sum); sq = wsum(sq);
  __shared__ float s1[4], s2[4];
  int lane = tid & 63, wave = tid >> 6;
  if (lane == 0){ s1[wave] = sum; s2[wave] = sq; }
  __syncthreads();
  if (tid == 0){
    atomicAdd(&zsum[layer*R + n], s1[0]+s1[1]+s1[2]+s1[3]);
    atomicAdd(&zsq [layer*R + n], s2[0]+s2[1]+s2[2]+s2[3]);
  }
}

// ---------------- BN stats for X1 ----------------
__global__ void k_xstats(const float* __restrict__ X1, float* __restrict__ xsum,
                         float* __restrict__ xsq, int layer){
  int n = blockIdx.x;
  int tid = threadIdx.x;
  float sum = 0.f, sq = 0.f;
  for (int idx = tid; idx < BATCH * 3; idx += 256){
    int bl = idx / 3, c = idx - bl * 3;
    float v = X1[((size_t)bl * R + n) * 3 + c];
    sum += v; sq += v * v;
  }
  sum = wsum(sum); sq = wsum(sq);
  __shared__ float s1[4], s2[4];
  int lane = tid & 63, wave = tid >> 6;
  if (lane == 0){ s1[wave] = sum; s2[wave] = sq; }
  __syncthreads();
  if (tid == 0){
    xsum[layer*R + n] = s1[0]+s1[1]+s1[2]+s1[3];
    xsq [layer*R + n] = s2[0]+s2[1]+s2[2]+s2[3];
  }
}

// ---------------- apply BN+relu+residual to Z (bf16 in/out) ----------------
__global__ void k_bnz(const ushort_t* __restrict__ Z1, ushort_t* __restrict__ Zc,
                      const float* __restrict__ zsum, const float* __restrict__ zsq,
                      const float* __restrict__ geg, const float* __restrict__ geb,
                      int layer){
  const float cnt = (float)(BATCH * R);
  int i = blockIdx.x * blockDim.x + threadIdx.x;
  int stride = gridDim.x * blockDim.x;
  for (int idx = i; idx < BATCH * RR2; idx += stride){
    int n = (idx / R) % R;
    float m = zsum[layer*R + n] / cnt;
    float v = fmaxf(zsq[layer*R + n] / cnt - m * m, 0.f);
    float rs = rsqrtf(v + EPSF);
    float val = (bf2f(Z1[idx]) - m) * rs * geg[layer*R + n] + geb[layer*R + n];
    Zc[idx] = f2bf(fmaxf(val, 0.f) + bf2f(Zc[idx]));
  }
}

__global__ void k_bnx(const float* __restrict__ X1, float* __restrict__ Xc,
                      const float* __restrict__ xsum, const float* __restrict__ xsq,
                      const float* __restrict__ gng, const float* __restrict__ gnb,
                      int layer){
  const float cnt = (float)(BATCH * 3);
  int idx = blockIdx.x * blockDim.x + threadIdx.x;   // exactly BATCH*R*3 threads
  if (idx >= BATCH * R * 3) return;
  int n = (idx / 3) % R;
  float m = xsum[layer*R + n] / cnt;
  float v = fmaxf(xsq[layer*R + n] / cnt - m * m, 0.f);
  float rs = rsqrtf(v + EPSF);
  float val = (X1[idx] - m) * rs * gng[layer*R + n] + gnb[layer*R + n];
  Xc[idx] = fmaxf(val, 0.f) + Xc[idx];
}

// ---------------- down-sample node ----------------
__global__ void k_dnode(const float* __restrict__ Xc, const float* __restrict__ dnw,
                        const float* __restrict__ dnb, float* __restrict__ fn,
                        float* __restrict__ dnS, int t){
  int idx = blockIdx.x * 256 + threadIdx.x;    // exactly BATCH*R
  float w0 = dnw[t*3+0], w1 = dnw[t*3+1], w2 = dnw[t*3+2];
  float bb = dnb[t];
  const float* x = Xc + (size_t)idx * 3;
  float f = fmaxf(w0*x[0] + w1*x[1] + w2*x[2] + bb, 0.f);
  fn[idx] = f;
  float s = wsum(f), q = wsum(f * f);
  __shared__ float s1[4], s2[4];
  int lane = threadIdx.x & 63, wave = threadIdx.x >> 6;
  if (lane == 0){ s1[wave] = s; s2[wave] = q; }
  __syncthreads();
  if (threadIdx.x == 0){
    atomicAdd(&dnS[t*2+0], s1[0]+s1[1]+s1[2]+s1[3]);
    atomicAdd(&dnS[t*2+1], s2[0]+s2[1]+s2[2]+s2[3]);
  }
}

__global__ void k_dnode_apply(const float* __restrict__ fn, const float* __restrict__ dnS,
                              const float* __restrict__ dng, const float* __restrict__ dnbe,
                              ushort_t* __restrict__ XZ, int t){
  int idx = blockIdx.x * 256 + threadIdx.x;    // BATCH*R
  const float cnt = (float)(BATCH * R);
  float m = dnS[t*2+0] / cnt;
  float v = fmaxf(dnS[t*2+1] / cnt - m * m, 0.f);
  float h = (fn[idx] - m) * rsqrtf(v + EPSF) * dng[t] + dnbe[t];
  int bi = idx / R, r = idx - bi * R;
  XZ[(size_t)bi * XZS + t*R + r] = f2bf(h);
}

// ---------------- down-sample edge ----------------
__global__ void k_dedge(const ushort_t* __restrict__ Zc, const float* __restrict__ dew,
                        const float* __restrict__ deb, float* __restrict__ fe,
                        float* __restrict__ deS, int t){
  __shared__ float wsm[78];
  if (threadIdx.x < 78) wsm[threadIdx.x] = dew[t*78 + threadIdx.x];
  __syncthreads();
  int idx = blockIdx.x * 256 + threadIdx.x;    // BATCH*R rows
  const ushort_t* x = Zc + (size_t)idx * R;
  float bb = deb[t];
  float f0 = 0.f, f1 = 0.f, f2 = 0.f;
  for (int j = 0; j < 78; j++){
    float w = wsm[j];
    if (j >= 39) f0 += w * bf2f(x[j - 39]);
    f1 += w * bf2f(x[j]);
    if (j < 77)  f2 += w * bf2f(x[j + 39]);
  }
  f0 = fmaxf(f0 + bb, 0.f); f1 = fmaxf(f1 + bb, 0.f); f2 = fmaxf(f2 + bb, 0.f);
  fe[(size_t)idx*3 + 0] = f0; fe[(size_t)idx*3 + 1] = f1; fe[(size_t)idx*3 + 2] = f2;
  float s = wsum(f0 + f1 + f2), q = wsum(f0*f0 + f1*f1 + f2*f2);
  __shared__ float s1[4], s2[4];
  int lane = threadIdx.x & 63, wave = threadIdx.x >> 6;
  if (lane == 0){ s1[wave] = s; s2[wave] = q; }
  __syncthreads();
  if (threadIdx.x == 0){
    atomicAdd(&deS[t*2+0], s1[0]+s1[1]+s1[2]+s1[3]);
    atomicAdd(&deS[t*2+1], s2[0]+s2[1]+s2[2]+s2[3]);
  }
}

__global__ void k_dedge_apply(const float* __restrict__ fe, const float* __restrict__ deS,
                              const float* __restrict__ deg, const float* __restrict__ debe,
                              ushort_t* __restrict__ XZ, int t){
  int idx = blockIdx.x * 256 + threadIdx.x;    // BATCH*R*3
  const float cnt = (float)(BATCH * R * 3);
  float m = deS[t*2+0] / cnt;
  float v = fmaxf(deS[t*2+1] / cnt - m * m, 0.f);
  float h = (fe[idx] - m) * rsqrtf(v + EPSF) * deg[t] + debe[t];
  int bi = idx / (R * 3), rem = idx - bi * (R * 3);
  XZ[(size_t)bi * XZS + 5*R + t*3*R + rem] = f2bf(h);
}

// ---------------- classifier: fc1 as bf16 MFMA GEMM ----------------
// C[m][n] = relu( sum_k XZ[m][k] * cw1p[n][k] + cb1[n] ), M=N=1024, K=XZS.
// Grid (16,16): block = 64x64 tile, 4 waves; wave w = m-strip 16 rows, 4 n-tiles.
__launch_bounds__(256)
__global__ void k_fc1(const ushort_t* __restrict__ XZ, const ushort_t* __restrict__ cw1p,
                      const float* __restrict__ cb1, float* __restrict__ H){
  const int tid  = threadIdx.x;
  const int lane = tid & 63;
  const int wave = tid >> 6;
  const int qm   = lane & 15;
  const int quad = lane >> 4;
  const int m0   = blockIdx.x * 64 + wave * 16;
  const int n0   = blockIdx.y * 64;

  const f32x4 vzero = {0.f, 0.f, 0.f, 0.f};
  f32x4 acc[4];
  #pragma unroll
  for (int t = 0; t < 4; t++) acc[t] = vzero;

  const ushort_t* arow = XZ + (size_t)(m0 + qm) * XZS;
  for (int kk = 0; kk < XZS; kk += 32){
    bf16x8 a = *(const bf16x8*)(arow + kk + quad*8);
    #pragma unroll
    for (int t = 0; t < 4; t++){
      const ushort_t* brow = cw1p + (size_t)(n0 + t*16 + qm) * XZS;
      bf16x8 bf = *(const bf16x8*)(brow + kk + quad*8);
      acc[t] = __builtin_amdgcn_mfma_f32_16x16x32_bf16(a, bf, acc[t], 0, 0, 0);
    }
  }
  #pragma unroll
  for (int t = 0; t < 4; t++){
    int n = n0 + t*16 + qm;
    float bias = cb1[n];
    #pragma unroll
    for (int rg = 0; rg < 4; rg++){
      int m = m0 + quad*4 + rg;
      H[(size_t)m * 1024 + n] = fmaxf(acc[t][rg] + bias, 0.f);
    }
  }
}

__global__ void k_fc2(const float* __restrict__ H, const float* __restrict__ cw2,
                      const float* __restrict__ cb2, float* __restrict__ out){
  int b = blockIdx.x, tid = threadIdx.x;
  float a0 = 0.f, a1 = 0.f;
  for (int j = tid; j < 1024; j += 256){
    float h = H[(size_t)b * 1024 + j];
    a0 += h * cw2[j];
    a1 += h * cw2[1024 + j];
  }
  a0 = wsum(a0); a1 = wsum(a1);
  __shared__ float s0[4], s1[4];
  int lane = tid & 63, wave = tid >> 6;
  if (lane == 0){ s0[wave] = a0; s1[wave] = a1; }
  __syncthreads();
  if (tid == 0){
    out[b*2 + 0] = s0[0]+s0[1]+s0[2]+s0[3] + cb2[0];   // fp32 output
    out[b*2 + 1] = s1[0]+s1[1]+s1[2]+s1[3] + cb2[1];
  }
}

extern "C" void kernel_launch(void* const* d_in, const int* in_sizes, int n_in,
                              void* d_out, int out_size, void* d_ws, size_t ws_size,
                              hipStream_t stream)
{
  const float* Xin  = (const float*)d_in[0];
  const float* Zin  = (const float*)d_in[1];
  const float* aw1  = (const float*)d_in[2];
  const float* ab1  = (const float*)d_in[3];
  const float* aw2  = (const float*)d_in[4];
  const float* ab2  = (const float*)d_in[5];
  const float* nw   = (const float*)d_in[6];
  const float* nb   = (const float*)d_in[7];
  const float* ew   = (const float*)d_in[8];
  const float* eb   = (const float*)d_in[9];
  const float* gng  = (const float*)d_in[10];
  const float* gnb  = (const float*)d_in[11];
  const float* geg  = (const float*)d_in[12];
  const float* geb  = (const float*)d_in[13];
  const float* dnw  = (const float*)d_in[14];
  const float* dnb  = (const float*)d_in[15];
  const float* dng  = (const float*)d_in[16];
  const float* dnbe = (const float*)d_in[17];
  const float* dew  = (const float*)d_in[18];
  const float* deb  = (const float*)d_in[19];
  const float* deg  = (const float*)d_in[20];
  const float* debe = (const float*)d_in[21];
  const float* cw1  = (const float*)d_in[22];
  const float* cb1  = (const float*)d_in[23];
  const float* cw2  = (const float*)d_in[24];
  const float* cb2  = (const float*)d_in[25];

  // ---- workspace layout: TOTAL 67,805,184 B = 64.7 MiB (ws >= 69.6 MB per R3 evidence) ----
  ushort_t* Zc = (ushort_t*)d_ws;            // bf16 Z state            27.56 MB
  ushort_t* Z1 = Zc + NZ_ELEM;               // bf16 pre-BN Z1          27.56 MB
  float*    fe = (float*)Z1;                 //   overlay: edge feats (Z1 dead when written)
  float*    H  = (float*)Z1;                 //   overlay: fc1 out     (fe dead when written)
  float*    Xc = (float*)(Z1 + NZ_ELEM);     // fp32 X state             1.43 MB
  float*    X1 = Xc + NX_ELEM;               // fp32 pre-BN X1           1.43 MB
  float*    fn = X1;                         //   overlay: node feats  (X1 dead when written)
  ushort_t* XZ = (ushort_t*)(X1 + NX_ELEM);  // bf16 features (B,XZS)    4.78 MB
  float*    st = (float*)(XZ + BATCH*XZS);   // stats: 2048 floats       8 KB
  ushort_t* aw2p = (ushort_t*)(st + 2048);   // bf16 aw2^T padded 4x128x128  128 KB
  ushort_t* ewp  = aw2p + 4*16384;           // bf16 ew    padded 4x128x128  128 KB
  ushort_t* cw1p = ewp + 4*16384;            // bf16 cw1 [n][k] K-padded     4.78 MB
  float* zsum = st;        float* zsq = st + 464;
  float* xsum = st + 928;  float* xsq = st + 1392;
  float* dnS  = st + 1856; float* deS = st + 1866;

  float* outp = (float*)d_out;

  // init: Z fp32->bf16, X copy + zero stats + zero XZ, pack MFMA weights
  k_initZ<<<2048, 256, 0, stream>>>((const float4*)Zin, (uint4*)Zc, NZ_ELEM / 8);
  k_initX<<<1392, 256, 0, stream>>>(Xin, Xc, NX_ELEM, st, 2048,
                                    (unsigned*)XZ, BATCH*XZS/2);
  k_initW<<<256, 256, 0, stream>>>(aw2, ew, aw2p, ewp);
  k_initC<<<9344, 256, 0, stream>>>(cw1, cw1p);

  // t = 0 snapshots
  k_dnode<<<464, 256, 0, stream>>>(Xc, dnw, dnb, fn, dnS, 0);
  k_dnode_apply<<<464, 256, 0, stream>>>(fn, dnS, dng, dnbe, XZ, 0);
  k_dedge<<<464, 256, 0, stream>>>(Zc, dew, deb, fe, deS, 0);
  k_dedge_apply<<<1392, 256, 0, stream>>>(fe, deS, deg, debe, XZ, 0);

  for (int i = 0; i < NL; i++){
    k_attn<<<BATCH, 1024, 0, stream>>>(Xc, Zc, Z1, X1, aw1, ab1, aw2p, ab2,
                                       nw, nb, ewp, eb, i);
    k_zstats<<<dim3(R, 16), 256, 0, stream>>>(Z1, zsum, zsq, i);
    k_xstats<<<R, 256, 0, stream>>>(X1, xsum, xsq, i);
    k_bnz<<<4096, 256, 0, stream>>>(Z1, Zc, zsum, zsq, geg, geb, i);
    k_bnx<<<1392, 256, 0, stream>>>(X1, Xc, xsum, xsq, gng, gnb, i);
    // fe/fn overlay Z1/X1: both are dead here (bnz/bnx consumed them)
    k_dedge<<<464, 256, 0, stream>>>(Zc, dew, deb, fe, deS, i + 1);
    k_dedge_apply<<<1392, 256, 0, stream>>>(fe, deS, deg, debe, XZ, i + 1);
    k_dnode<<<464, 256, 0, stream>>>(Xc, dnw, dnb, fn, dnS, i + 1);
    k_dnode_apply<<<464, 256, 0, stream>>>(fn, dnS, dng, dnbe, XZ, i + 1);
  }

  k_fc1<<<dim3(16, 16), 256, 0, stream>>>(XZ, cw1p, cb1, H);
  k_fc2<<<BATCH, 256, 0, stream>>>(H, cw2, cb2, outp);
}